// Round 1
// baseline (284.427 us; speedup 1.0000x reference)
//
#include <hip/hip_runtime.h>
#include <math.h>

typedef unsigned short u16t;
typedef __attribute__((ext_vector_type(8))) __bf16 bf16x8;
typedef __attribute__((ext_vector_type(4))) float f32x4;
typedef __attribute__((ext_vector_type(4))) unsigned short u16x4;

__device__ __forceinline__ u16t f2bf(float f) {
  union { float f; unsigned u; } v; v.f = f;
  return (u16t)((v.u + 0x7FFFu + ((v.u >> 16) & 1u)) >> 16);
}

// ---------------- elementwise f32 -> bf16 ----------------
__global__ __launch_bounds__(256) void k_cvt_bf16(const float* __restrict__ in,
                                                  u16t* __restrict__ out, int n4) {
  int i = blockIdx.x * 256 + threadIdx.x;
  if (i >= n4) return;
  f32x4 x = reinterpret_cast<const f32x4*>(in)[i];
  u16x4 y;
#pragma unroll
  for (int j = 0; j < 4; j++) y[j] = f2bf(x[j]);
  reinterpret_cast<u16x4*>(out)[i] = y;
}

// ---------------- transpose f32[R][C] -> bf16[C][R] ----------------
__global__ __launch_bounds__(256) void k_transpose(const float* __restrict__ in,
                                                   u16t* __restrict__ out, int R, int C) {
  __shared__ u16t tile[64][68];
  int r0 = blockIdx.y * 64, c0 = blockIdx.x * 64;
  int t = threadIdx.x;
  int rr = t >> 4, q4 = (t & 15) * 4;
#pragma unroll
  for (int i = 0; i < 4; i++) {
    int r = rr + i * 16;
    f32x4 x = *reinterpret_cast<const f32x4*>(&in[(size_t)(r0 + r) * C + c0 + q4]);
#pragma unroll
    for (int j = 0; j < 4; j++) tile[r][q4 + j] = f2bf(x[j]);
  }
  __syncthreads();
#pragma unroll
  for (int i = 0; i < 4; i++) {
    int c = rr + i * 16;
    u16x4 y;
#pragma unroll
    for (int j = 0; j < 4; j++) y[j] = tile[q4 + j][c];
    *reinterpret_cast<u16x4*>(&out[(size_t)(c0 + c) * R + r0 + q4]) = y;
  }
}

// ---------------- GEMM: C[M][N] = A_bf16[M][K] @ Bt_bf16[N][K] + bias ----------------
__global__ __launch_bounds__(256) void k_gemm_bias(const u16t* __restrict__ A,
                                                   const u16t* __restrict__ Bt,
                                                   const float* __restrict__ bias,
                                                   float* __restrict__ C,
                                                   int M, int N, int K) {
  __shared__ __align__(16) u16t As[64 * 64];
  __shared__ __align__(16) u16t Bs[64 * 64];
  int m0 = blockIdx.y * 64, n0 = blockIdx.x * 64;
  int t = threadIdx.x, lane = t & 63, w = t >> 6;
  int l15 = lane & 15, l16 = lane >> 4;
  int sr = t >> 4, sc8 = t & 15;
  f32x4 acc[4] = {f32x4{0,0,0,0}, f32x4{0,0,0,0}, f32x4{0,0,0,0}, f32x4{0,0,0,0}};

  for (int kt = 0; kt < K; kt += 64) {
#pragma unroll
    for (int i = 0; i < 4; i++) {
      int row = sr + i * 16;
      u16x4 a = *reinterpret_cast<const u16x4*>(&A[(size_t)(m0 + row) * K + kt + sc8 * 4]);
      u16x4 b = *reinterpret_cast<const u16x4*>(&Bt[(size_t)(n0 + row) * K + kt + sc8 * 4]);
      int byte = row * 128 + ((sc8 * 8) ^ ((row & 7) << 4));
      *reinterpret_cast<u16x4*>(((char*)As) + byte) = a;
      *reinterpret_cast<u16x4*>(((char*)Bs) + byte) = b;
    }
    __syncthreads();
    int arow = w * 16 + l15;
    int kb = l16 * 16;
#pragma unroll
    for (int kk = 0; kk < 2; kk++) {
      bf16x8 af = *reinterpret_cast<const bf16x8*>(((char*)As) + arow * 128 + ((kk * 64 + kb) ^ ((arow & 7) << 4)));
#pragma unroll
      for (int nf = 0; nf < 4; nf++) {
        int bcol = nf * 16 + l15;
        bf16x8 bfv = *reinterpret_cast<const bf16x8*>(((char*)Bs) + bcol * 128 + ((kk * 64 + kb) ^ ((bcol & 7) << 4)));
        acc[nf] = __builtin_amdgcn_mfma_f32_16x16x32_bf16(af, bfv, acc[nf], 0, 0, 0);
      }
    }
    __syncthreads();
  }
  int crow = m0 + w * 16 + l16 * 4;
#pragma unroll
  for (int nf = 0; nf < 4; nf++) {
    int col = n0 + nf * 16 + l15;
    float bb = bias[col];
#pragma unroll
    for (int r = 0; r < 4; r++) {
      C[(size_t)(crow + r) * N + col] = acc[nf][r] + bb;
    }
  }
}

// ---------------- ELU + per-head L2 norm -> bf16 (rows of 1024 = 16 heads x 64) ----------------
__global__ __launch_bounds__(256) void k_elu_norm(const float* __restrict__ in,
                                                  u16t* __restrict__ out) {
  int row = blockIdx.x, t = threadIdx.x;
  f32x4 x = *reinterpret_cast<const f32x4*>(&in[(size_t)row * 1024 + t * 4]);
  f32x4 e;
#pragma unroll
  for (int j = 0; j < 4; j++) e[j] = x[j] > 0.f ? x[j] : expm1f(x[j]);
  float ss = e[0] * e[0] + e[1] * e[1] + e[2] * e[2] + e[3] * e[3];
#pragma unroll
  for (int m = 1; m < 16; m <<= 1) ss += __shfl_xor(ss, m);
  float rinv = rsqrtf(ss);
  u16x4 y;
#pragma unroll
  for (int j = 0; j < 4; j++) y[j] = f2bf(e[j] * rinv);
  *reinterpret_cast<u16x4*>(&out[(size_t)row * 1024 + t * 4]) = y;
}

// ---------------- fused attention (no-max softmax: logits in [-0.125,0.125]) ----------------
// grid: (L/64, B*H). qn[4096][1024], kn[2048][1024], vT[1024][2048], ctx[4096][1024] bf16
__global__ __launch_bounds__(256) void k_attn(const u16t* __restrict__ qn,
                                              const u16t* __restrict__ kn,
                                              const u16t* __restrict__ vT,
                                              u16t* __restrict__ ctx) {
  __shared__ __align__(16) u16t kls[64 * 64];   // [key][e] swizzled
  __shared__ __align__(16) u16t vls[64 * 72];   // [e][key] pad to 72
  __shared__ __align__(16) u16t pls[4][16 * 64]; // per-wave P tile [qrow][key] swizzled
  int bh = blockIdx.y;
  int b = bh >> 4, h = bh & 15;
  int qt = blockIdx.x;
  int t = threadIdx.x, lane = t & 63, w = t >> 6;
  int l15 = lane & 15, l16 = lane >> 4;
  int sr = t >> 4, sc = t & 15;
  char* pbase = ((char*)pls) + w * 2048;

  size_t qrow = (size_t)b * 2048 + qt * 64 + w * 16 + l15;
  const u16t* qp = qn + qrow * 1024 + h * 64 + l16 * 8;
  bf16x8 qf0 = *reinterpret_cast<const bf16x8*>(qp);
  bf16x8 qf1 = *reinterpret_cast<const bf16x8*>(qp + 32);

  f32x4 acc[4] = {f32x4{0,0,0,0}, f32x4{0,0,0,0}, f32x4{0,0,0,0}, f32x4{0,0,0,0}};
  float rsum[4] = {0.f, 0.f, 0.f, 0.f};

  for (int k0 = 0; k0 < 2048; k0 += 64) {
    // stage K chunk [64 keys][64 e] (swizzled) and V^T chunk [64 e][64 keys] (padded)
#pragma unroll
    for (int i = 0; i < 4; i++) {
      int rowi = sr + i * 16;
      u16x4 kv = *reinterpret_cast<const u16x4*>(&kn[(size_t)(k0 + rowi) * 1024 + h * 64 + sc * 4]);
      int byte = rowi * 128 + ((sc * 8) ^ ((rowi & 7) << 4));
      *reinterpret_cast<u16x4*>(((char*)kls) + byte) = kv;
      u16x4 vv = *reinterpret_cast<const u16x4*>(&vT[(size_t)(h * 64 + rowi) * 2048 + k0 + sc * 4]);
      *reinterpret_cast<u16x4*>(((char*)vls) + rowi * 144 + sc * 8) = vv;
    }
    __syncthreads();

    // scores for this wave's 16 q-rows x 64 keys; exp; stash P (bf16) in per-wave LDS
#pragma unroll
    for (int nf = 0; nf < 4; nf++) {
      int key = nf * 16 + l15;
      int kb = l16 * 16;
      bf16x8 b0 = *reinterpret_cast<const bf16x8*>(((char*)kls) + key * 128 + ((kb) ^ ((key & 7) << 4)));
      bf16x8 b1 = *reinterpret_cast<const bf16x8*>(((char*)kls) + key * 128 + ((64 + kb) ^ ((key & 7) << 4)));
      f32x4 s = {0.f, 0.f, 0.f, 0.f};
      s = __builtin_amdgcn_mfma_f32_16x16x32_bf16(qf0, b0, s, 0, 0, 0);
      s = __builtin_amdgcn_mfma_f32_16x16x32_bf16(qf1, b1, s, 0, 0, 0);
#pragma unroll
      for (int r = 0; r < 4; r++) {
        float p = __expf(s[r] * 0.125f);
        rsum[r] += p;
        int prow = l16 * 4 + r;
        int pbyte = prow * 128 + ((key * 2) ^ ((prow & 7) << 4));
        *(u16t*)(pbase + pbyte) = f2bf(p);
      }
    }

    // PV: acc += P[16 x 64keys] @ V[64keys x 64e]
#pragma unroll
    for (int kk = 0; kk < 2; kk++) {
      bf16x8 pa = *reinterpret_cast<const bf16x8*>(pbase + l15 * 128 + ((kk * 64 + l16 * 16) ^ ((l15 & 7) << 4)));
#pragma unroll
      for (int nf = 0; nf < 4; nf++) {
        int e = nf * 16 + l15;
        bf16x8 bv = *reinterpret_cast<const bf16x8*>(((char*)vls) + e * 144 + kk * 64 + l16 * 16);
        acc[nf] = __builtin_amdgcn_mfma_f32_16x16x32_bf16(pa, bv, acc[nf], 0, 0, 0);
      }
    }
    __syncthreads();
  }

#pragma unroll
  for (int m = 1; m < 16; m <<= 1) {
#pragma unroll
    for (int r = 0; r < 4; r++) rsum[r] += __shfl_xor(rsum[r], m);
  }
  size_t orow = (size_t)b * 2048 + qt * 64 + w * 16 + l16 * 4;
#pragma unroll
  for (int nf = 0; nf < 4; nf++) {
    int col = h * 64 + nf * 16 + l15;
#pragma unroll
    for (int r = 0; r < 4; r++) {
      ctx[(orow + r) * 1024 + col] = f2bf(acc[nf][r] / rsum[r]);
    }
  }
}

// ---------------- residual + LayerNorm ----------------
__global__ __launch_bounds__(256) void k_out_ln(const float* __restrict__ Hh,
                                                const float* __restrict__ target,
                                                const float* __restrict__ g,
                                                const float* __restrict__ bb,
                                                float* __restrict__ out) {
  __shared__ float s_s[4], s_ss[4];
  int row = blockIdx.x, t = threadIdx.x, w = t >> 6;
  f32x4 hv = *reinterpret_cast<const f32x4*>(&Hh[(size_t)row * 1024 + t * 4]);
  f32x4 tv = *reinterpret_cast<const f32x4*>(&target[(size_t)row * 1024 + t * 4]);
  f32x4 x;
#pragma unroll
  for (int j = 0; j < 4; j++) x[j] = hv[j] + tv[j];
  float s = x[0] + x[1] + x[2] + x[3];
  float ss = x[0] * x[0] + x[1] * x[1] + x[2] * x[2] + x[3] * x[3];
#pragma unroll
  for (int m = 1; m < 64; m <<= 1) { s += __shfl_xor(s, m); ss += __shfl_xor(ss, m); }
  if ((t & 63) == 0) { s_s[w] = s; s_ss[w] = ss; }
  __syncthreads();
  s = s_s[0] + s_s[1] + s_s[2] + s_s[3];
  ss = s_ss[0] + s_ss[1] + s_ss[2] + s_ss[3];
  float mu = s * (1.f / 1024.f);
  float var = ss * (1.f / 1024.f) - mu * mu;
  float rs = rsqrtf(var + 1e-12f);
  f32x4 gv = *reinterpret_cast<const f32x4*>(&g[t * 4]);
  f32x4 bv = *reinterpret_cast<const f32x4*>(&bb[t * 4]);
  f32x4 o;
#pragma unroll
  for (int j = 0; j < 4; j++) o[j] = (x[j] - mu) * rs * gv[j] + bv[j];
  *reinterpret_cast<f32x4*>(&out[(size_t)row * 1024 + t * 4]) = o;
}

extern "C" void kernel_launch(void* const* d_in, const int* in_sizes, int n_in,
                              void* d_out, int out_size, void* d_ws, size_t ws_size,
                              hipStream_t stream) {
  const float* target = (const float*)d_in[0];
  const float* source = (const float*)d_in[1];
  const float* value  = (const float*)d_in[2];
  const float* Wq = (const float*)d_in[3];
  const float* bq = (const float*)d_in[4];
  const float* Wk = (const float*)d_in[5];
  const float* bk = (const float*)d_in[6];
  const float* Wv = (const float*)d_in[7];
  const float* bv = (const float*)d_in[8];
  const float* Wo = (const float*)d_in[9];
  const float* bo = (const float*)d_in[10];
  const float* lng = (const float*)d_in[11];
  const float* lnb = (const float*)d_in[12];
  float* out = (float*)d_out;
  char* ws = (char*)d_ws;

  const int MQ = 4096, S = 2048, D = 1024;
  const size_t MB = 1u << 20;
  u16t* t_bf  = (u16t*)(ws + 0 * MB);    // 8 MB
  u16t* s_bf  = (u16t*)(ws + 8 * MB);    // 4 MB
  u16t* vi_bf = (u16t*)(ws + 12 * MB);   // 4 MB
  u16t* Wqt   = (u16t*)(ws + 16 * MB);   // 2 MB
  u16t* Wkt   = (u16t*)(ws + 18 * MB);
  u16t* Wvt   = (u16t*)(ws + 20 * MB);
  u16t* Wot   = (u16t*)(ws + 22 * MB);
  float* Qf   = (float*)(ws + 24 * MB);  // 16 MB (reused as H)
  float* Kf   = (float*)(ws + 40 * MB);  // 8 MB (reused as ctx bf16)
  float* Vf   = (float*)(ws + 48 * MB);  // 8 MB
  u16t* qnb   = (u16t*)(ws + 56 * MB);   // 8 MB
  u16t* knb   = (u16t*)(ws + 64 * MB);   // 4 MB
  u16t* vTb   = (u16t*)(ws + 68 * MB);   // 4 MB; total 72 MB
  u16t* ctxb  = (u16t*)Kf;
  float* Hf   = Qf;

  k_cvt_bf16<<<dim3((MQ * D / 4 + 255) / 256), 256, 0, stream>>>(target, t_bf, MQ * D / 4);
  k_cvt_bf16<<<dim3((S * D / 4 + 255) / 256), 256, 0, stream>>>(source, s_bf, S * D / 4);
  k_cvt_bf16<<<dim3((S * D / 4 + 255) / 256), 256, 0, stream>>>(value, vi_bf, S * D / 4);

  k_transpose<<<dim3(16, 16), 256, 0, stream>>>(Wq, Wqt, 1024, 1024);
  k_transpose<<<dim3(16, 16), 256, 0, stream>>>(Wk, Wkt, 1024, 1024);
  k_transpose<<<dim3(16, 16), 256, 0, stream>>>(Wv, Wvt, 1024, 1024);
  k_transpose<<<dim3(16, 16), 256, 0, stream>>>(Wo, Wot, 1024, 1024);

  k_gemm_bias<<<dim3(16, 64), 256, 0, stream>>>(t_bf, Wqt, bq, Qf, MQ, 1024, 1024);
  k_gemm_bias<<<dim3(16, 32), 256, 0, stream>>>(s_bf, Wkt, bk, Kf, S, 1024, 1024);
  k_gemm_bias<<<dim3(16, 32), 256, 0, stream>>>(vi_bf, Wvt, bv, Vf, S, 1024, 1024);

  k_elu_norm<<<dim3(4096), 256, 0, stream>>>(Qf, qnb);
  k_elu_norm<<<dim3(2048), 256, 0, stream>>>(Kf, knb);
  k_transpose<<<dim3(16, 32), 256, 0, stream>>>(Vf, vTb, 2048, 1024);

  k_attn<<<dim3(32, 32), 256, 0, stream>>>(qnb, knb, vTb, ctxb);

  k_gemm_bias<<<dim3(16, 64), 256, 0, stream>>>(ctxb, Wot, bo, Hf, MQ, 1024, 1024);

  k_out_ln<<<dim3(4096), 256, 0, stream>>>(Hf, target, lng, lnb, out);
}

// Round 2
// 158.685 us; speedup vs baseline: 1.7924x; 1.7924x over previous
//
#include <hip/hip_runtime.h>
#include <math.h>

typedef unsigned short u16t;
typedef __attribute__((ext_vector_type(8))) __bf16 bf16x8;
typedef __attribute__((ext_vector_type(4))) float f32x4;
typedef __attribute__((ext_vector_type(4))) unsigned short u16x4;

__device__ __forceinline__ u16t f2bf(float f) {
  union { float f; unsigned u; } v; v.f = f;
  return (u16t)((v.u + 0x7FFFu + ((v.u >> 16) & 1u)) >> 16);
}

// async global->LDS, 16B per lane; LDS dest must be linear (wave-uniform base + lane*16)
__device__ __forceinline__ void gload_lds16(const void* g, void* l) {
  __builtin_amdgcn_global_load_lds(
      (__attribute__((address_space(1))) void*)(uintptr_t)g,
      (__attribute__((address_space(3))) void*)(unsigned)(uintptr_t)l,
      16, 0, 0);
}

// ---------------- elementwise f32 -> bf16 ----------------
__global__ __launch_bounds__(256) void k_cvt_bf16(const float* __restrict__ in,
                                                  u16t* __restrict__ out, int n4) {
  int i = blockIdx.x * 256 + threadIdx.x;
  if (i >= n4) return;
  f32x4 x = reinterpret_cast<const f32x4*>(in)[i];
  u16x4 y;
#pragma unroll
  for (int j = 0; j < 4; j++) y[j] = f2bf(x[j]);
  reinterpret_cast<u16x4*>(out)[i] = y;
}

// ---------------- transpose f32[R][C] -> bf16[C][R] ----------------
__global__ __launch_bounds__(256) void k_transpose(const float* __restrict__ in,
                                                   u16t* __restrict__ out, int R, int C) {
  __shared__ u16t tile[64][68];
  int r0 = blockIdx.y * 64, c0 = blockIdx.x * 64;
  int t = threadIdx.x;
  int rr = t >> 4, q4 = (t & 15) * 4;
#pragma unroll
  for (int i = 0; i < 4; i++) {
    int r = rr + i * 16;
    f32x4 x = *reinterpret_cast<const f32x4*>(&in[(size_t)(r0 + r) * C + c0 + q4]);
#pragma unroll
    for (int j = 0; j < 4; j++) tile[r][q4 + j] = f2bf(x[j]);
  }
  __syncthreads();
#pragma unroll
  for (int i = 0; i < 4; i++) {
    int c = rr + i * 16;
    u16x4 y;
#pragma unroll
    for (int j = 0; j < 4; j++) y[j] = tile[q4 + j][c];
    *reinterpret_cast<u16x4*>(&out[(size_t)(c0 + c) * R + r0 + q4]) = y;
  }
}

// ---------------- 128x128 GEMM body: C[M][1024] = A[M][1024] @ Bt[1024][1024]^T + bias ----
// K = N = ld = 1024 fixed. global_load_lds staging with pre-swizzled source so LDS is
// XOR-swizzled: byte o of row r stored at o ^ ((r&7)<<4).
__device__ __forceinline__ void gemm128_body(const u16t* __restrict__ A,
                                             const u16t* __restrict__ Bt,
                                             const float* __restrict__ bias,
                                             float* __restrict__ C,
                                             int m0, int n0) {
  __shared__ __align__(16) u16t As[128 * 64];
  __shared__ __align__(16) u16t Bs[128 * 64];
  int t = threadIdx.x, lane = t & 63, w = t >> 6;
  int l15 = lane & 15, l16 = lane >> 4;
  int wr = w >> 1, wc = w & 1;
  f32x4 acc[4][4] = {};
  int srow = t >> 3;                       // 0..31
  int slc = ((t & 7) ^ (srow & 7)) << 3;   // pre-swizzled source chunk (elements)

  for (int kt = 0; kt < 1024; kt += 64) {
#pragma unroll
    for (int i = 0; i < 4; i++) {
      int row = srow + i * 32;             // row&7 invariant over i
      int c16 = (t + i * 256) * 16;
      gload_lds16(A + ((size_t)(m0 + row) << 10) + kt + slc, (char*)As + c16);
      gload_lds16(Bt + ((size_t)(n0 + row) << 10) + kt + slc, (char*)Bs + c16);
    }
    __syncthreads();
#pragma unroll
    for (int kk = 0; kk < 2; kk++) {
      bf16x8 af[4], bfr[4];
#pragma unroll
      for (int m = 0; m < 4; m++) {
        int ar = wr * 64 + m * 16 + l15;
        af[m] = *(const bf16x8*)((char*)As + ar * 128 + ((kk * 64 + l16 * 16) ^ ((ar & 7) << 4)));
      }
#pragma unroll
      for (int n = 0; n < 4; n++) {
        int br = wc * 64 + n * 16 + l15;
        bfr[n] = *(const bf16x8*)((char*)Bs + br * 128 + ((kk * 64 + l16 * 16) ^ ((br & 7) << 4)));
      }
#pragma unroll
      for (int m = 0; m < 4; m++)
#pragma unroll
        for (int n = 0; n < 4; n++)
          acc[m][n] = __builtin_amdgcn_mfma_f32_16x16x32_bf16(af[m], bfr[n], acc[m][n], 0, 0, 0);
    }
    __syncthreads();
  }
#pragma unroll
  for (int n = 0; n < 4; n++) {
    int col = n0 + wc * 64 + n * 16 + l15;
    float bb = bias[col];
#pragma unroll
    for (int m = 0; m < 4; m++) {
      int row = m0 + wr * 64 + m * 16 + l16 * 4;
#pragma unroll
      for (int r = 0; r < 4; r++)
        C[((size_t)(row + r) << 10) + col] = acc[m][n][r] + bb;
    }
  }
}

// fused QKV: A rows 0..4095 = target (Wq,bq), 4096..6143 = source (Wk,bk), 6144..8191 = value (Wv,bv)
__global__ __launch_bounds__(256) void k_gemm_qkv(const u16t* __restrict__ A,
                                                  const u16t* __restrict__ Wt,
                                                  const float* __restrict__ b0,
                                                  const float* __restrict__ b1,
                                                  const float* __restrict__ b2,
                                                  float* __restrict__ C) {
  int m0 = blockIdx.y * 128, n0 = blockIdx.x * 128;
  int seg = (m0 >= 6144) ? 2 : (m0 >= 4096) ? 1 : 0;
  const float* bias = (seg == 0) ? b0 : (seg == 1) ? b1 : b2;
  gemm128_body(A, Wt + ((size_t)seg << 20), bias, C, m0, n0);
}

__global__ __launch_bounds__(256) void k_gemm_o(const u16t* __restrict__ A,
                                                const u16t* __restrict__ Wt,
                                                const float* __restrict__ bias,
                                                float* __restrict__ C) {
  gemm128_body(A, Wt, bias, C, blockIdx.y * 128, blockIdx.x * 128);
}

// ---------------- ELU + per-head L2 norm -> bf16 ----------------
__global__ __launch_bounds__(256) void k_elu_norm(const float* __restrict__ in,
                                                  u16t* __restrict__ out) {
  int row = blockIdx.x, t = threadIdx.x;
  f32x4 x = *reinterpret_cast<const f32x4*>(&in[(size_t)row * 1024 + t * 4]);
  f32x4 e;
#pragma unroll
  for (int j = 0; j < 4; j++) e[j] = x[j] > 0.f ? x[j] : expm1f(x[j]);
  float ss = e[0] * e[0] + e[1] * e[1] + e[2] * e[2] + e[3] * e[3];
#pragma unroll
  for (int m = 1; m < 16; m <<= 1) ss += __shfl_xor(ss, m);
  float rinv = rsqrtf(ss);
  u16x4 y;
#pragma unroll
  for (int j = 0; j < 4; j++) y[j] = f2bf(e[j] * rinv);
  *reinterpret_cast<u16x4*>(&out[(size_t)row * 1024 + t * 4]) = y;
}

// ---------------- fused attention ----------------
// Swapped QK^T (mfma(K,Q) -> S^T): lane holds 4 consecutive keys for q-row l15.
// No-max softmax: logits in [-0.128, 0.128]; exp via cubic poly.
// grid: (L/64, B*H). qn[4096][1024], kn[2048][1024], vT[1024][2048], ctx[4096][1024] bf16
__global__ __launch_bounds__(256) void k_attn(const u16t* __restrict__ qn,
                                              const u16t* __restrict__ kn,
                                              const u16t* __restrict__ vT,
                                              u16t* __restrict__ ctx) {
  __shared__ __align__(16) u16t kls[64 * 64];     // [key][e], XOR-swizzled
  __shared__ __align__(16) u16t vls[64 * 64];     // [e][key], XOR-swizzled
  __shared__ __align__(16) u16t pls[4][16 * 64];  // per-wave P [qrow16][key64], swizzled
  int bh = blockIdx.y, b = bh >> 4, h = bh & 15;
  int qt = blockIdx.x;
  int t = threadIdx.x, lane = t & 63, w = t >> 6;
  int l15 = lane & 15, l16 = lane >> 4;
  char* pbase = (char*)pls + w * 2048;

  size_t qrow = (size_t)b * 2048 + qt * 64 + w * 16 + l15;
  const u16t* qp = qn + (qrow << 10) + (h << 6) + l16 * 8;
  bf16x8 qf0 = *(const bf16x8*)qp;
  bf16x8 qf1 = *(const bf16x8*)(qp + 32);

  f32x4 acc[4] = {};
  float rsum = 0.f;
  int srow = t >> 3, scc = t & 7;
  int slc = (scc ^ (srow & 7)) << 3;
  int kswz = (l15 & 7) << 4;

  for (int k0 = 0; k0 < 2048; k0 += 64) {
#pragma unroll
    for (int i = 0; i < 2; i++) {
      int row = srow + i * 32;
      int c16 = (t + i * 256) * 16;
      gload_lds16(kn + ((size_t)(k0 + row) << 10) + (h << 6) + slc, (char*)kls + c16);
      gload_lds16(vT + ((size_t)((h << 6) + row) << 11) + k0 + slc, (char*)vls + c16);
    }
    __syncthreads();

    // S^T = K . Q^T ; P = poly-exp ; packed b64 stores into per-wave P tile
#pragma unroll
    for (int nf = 0; nf < 4; nf++) {
      int key = nf * 16 + l15;
      bf16x8 a0 = *(const bf16x8*)((char*)kls + key * 128 + ((l16 * 16) ^ kswz));
      bf16x8 a1 = *(const bf16x8*)((char*)kls + key * 128 + ((64 + l16 * 16) ^ kswz));
      f32x4 s = {};
      s = __builtin_amdgcn_mfma_f32_16x16x32_bf16(a0, qf0, s, 0, 0, 0);
      s = __builtin_amdgcn_mfma_f32_16x16x32_bf16(a1, qf1, s, 0, 0, 0);
      float p[4];
#pragma unroll
      for (int r = 0; r < 4; r++) {
        float x = s[r] * 0.125f;
        p[r] = fmaf(x, fmaf(x, fmaf(x, 0.16666667f, 0.5f), 1.f), 1.f);
      }
      rsum += (p[0] + p[1]) + (p[2] + p[3]);
      unsigned w0, w1;
      asm("v_cvt_pk_bf16_f32 %0, %1, %2" : "=v"(w0) : "v"(p[0]), "v"(p[1]));
      asm("v_cvt_pk_bf16_f32 %0, %1, %2" : "=v"(w1) : "v"(p[2]), "v"(p[3]));
      union { unsigned u[2]; unsigned long long ull; } pw;
      pw.u[0] = w0; pw.u[1] = w1;
      *(unsigned long long*)(pbase + l15 * 128 + ((nf * 32 + l16 * 8) ^ kswz)) = pw.ull;
    }

    // PV: acc += P[16 x 64] @ V[64 x 64]
#pragma unroll
    for (int kk = 0; kk < 2; kk++) {
      bf16x8 pa = *(const bf16x8*)(pbase + l15 * 128 + ((kk * 64 + l16 * 16) ^ kswz));
#pragma unroll
      for (int nf = 0; nf < 4; nf++) {
        int e = nf * 16 + l15;
        bf16x8 bv = *(const bf16x8*)((char*)vls + e * 128 + ((kk * 64 + l16 * 16) ^ ((e & 7) << 4)));
        acc[nf] = __builtin_amdgcn_mfma_f32_16x16x32_bf16(pa, bv, acc[nf], 0, 0, 0);
      }
    }
    __syncthreads();
  }

  rsum += __shfl_xor(rsum, 16);
  rsum += __shfl_xor(rsum, 32);
  float rinv[4];
#pragma unroll
  for (int r = 0; r < 4; r++) rinv[r] = 1.f / __shfl(rsum, l16 * 4 + r);
  size_t orow = (size_t)b * 2048 + qt * 64 + w * 16 + l16 * 4;
#pragma unroll
  for (int nf = 0; nf < 4; nf++) {
    int col = (h << 6) + nf * 16 + l15;
#pragma unroll
    for (int r = 0; r < 4; r++)
      ctx[((orow + r) << 10) + col] = f2bf(acc[nf][r] * rinv[r]);
  }
}

// ---------------- residual + LayerNorm ----------------
__global__ __launch_bounds__(256) void k_out_ln(const float* __restrict__ Hh,
                                                const float* __restrict__ target,
                                                const float* __restrict__ g,
                                                const float* __restrict__ bb,
                                                float* __restrict__ out) {
  __shared__ float s_s[4], s_ss[4];
  int row = blockIdx.x, t = threadIdx.x, w = t >> 6;
  f32x4 hv = *reinterpret_cast<const f32x4*>(&Hh[(size_t)row * 1024 + t * 4]);
  f32x4 tv = *reinterpret_cast<const f32x4*>(&target[(size_t)row * 1024 + t * 4]);
  f32x4 x;
#pragma unroll
  for (int j = 0; j < 4; j++) x[j] = hv[j] + tv[j];
  float s = x[0] + x[1] + x[2] + x[3];
  float ss = x[0] * x[0] + x[1] * x[1] + x[2] * x[2] + x[3] * x[3];
#pragma unroll
  for (int m = 1; m < 64; m <<= 1) { s += __shfl_xor(s, m); ss += __shfl_xor(ss, m); }
  if ((t & 63) == 0) { s_s[w] = s; s_ss[w] = ss; }
  __syncthreads();
  s = s_s[0] + s_s[1] + s_s[2] + s_s[3];
  ss = s_ss[0] + s_ss[1] + s_ss[2] + s_ss[3];
  float mu = s * (1.f / 1024.f);
  float var = ss * (1.f / 1024.f) - mu * mu;
  float rs = rsqrtf(var + 1e-12f);
  f32x4 gv = *reinterpret_cast<const f32x4*>(&g[t * 4]);
  f32x4 bv = *reinterpret_cast<const f32x4*>(&bb[t * 4]);
  f32x4 o;
#pragma unroll
  for (int j = 0; j < 4; j++) o[j] = (x[j] - mu) * rs * gv[j] + bv[j];
  *reinterpret_cast<f32x4*>(&out[(size_t)row * 1024 + t * 4]) = o;
}

extern "C" void kernel_launch(void* const* d_in, const int* in_sizes, int n_in,
                              void* d_out, int out_size, void* d_ws, size_t ws_size,
                              hipStream_t stream) {
  const float* target = (const float*)d_in[0];
  const float* source = (const float*)d_in[1];
  const float* value  = (const float*)d_in[2];
  const float* Wq = (const float*)d_in[3];
  const float* bq = (const float*)d_in[4];
  const float* Wk = (const float*)d_in[5];
  const float* bk = (const float*)d_in[6];
  const float* Wv = (const float*)d_in[7];
  const float* bv = (const float*)d_in[8];
  const float* Wo = (const float*)d_in[9];
  const float* bo = (const float*)d_in[10];
  const float* lng = (const float*)d_in[11];
  const float* lnb = (const float*)d_in[12];
  float* out = (float*)d_out;
  char* ws = (char*)d_ws;
  const size_t MB = 1u << 20;

  // ws layout (56 MB):
  //  [0,32)   QKVf f32 [8192][1024]  (Q rows 0-4095, K 4096-6143, V 6144-8191); later Hf = rows 0-4095
  //  [16,24)  ctxb bf16 [4096][1024] (overlays Kf after elu_norm(K))
  //  [32,48)  abf bf16 [8192][1024]  (target/source/value); later qnb/knb/vTb
  //  [48,54)  Wt bf16 3 x [1024][1024] (Wq^T, Wk^T, Wv^T)
  //  [54,56)  Wot bf16 [1024][1024]
  float* QKVf = (float*)ws;
  u16t* ctxb = (u16t*)(ws + 16 * MB);
  u16t* abf  = (u16t*)(ws + 32 * MB);
  u16t* Wt   = (u16t*)(ws + 48 * MB);
  u16t* Wot  = (u16t*)(ws + 54 * MB);
  float* Qf = QKVf;
  float* Kf = QKVf + (size_t)4096 * 1024;
  float* Vf = QKVf + (size_t)6144 * 1024;
  u16t* t_bf  = abf;
  u16t* s_bf  = abf + (size_t)4096 * 1024;
  u16t* vi_bf = abf + (size_t)6144 * 1024;
  u16t* qnb = (u16t*)(ws + 32 * MB);
  u16t* knb = (u16t*)(ws + 40 * MB);
  u16t* vTb = (u16t*)(ws + 44 * MB);
  float* Hf = QKVf;

  k_cvt_bf16<<<dim3(4096), 256, 0, stream>>>(target, t_bf, 1048576);
  k_cvt_bf16<<<dim3(2048), 256, 0, stream>>>(source, s_bf, 524288);
  k_cvt_bf16<<<dim3(2048), 256, 0, stream>>>(value, vi_bf, 524288);

  k_transpose<<<dim3(16, 16), 256, 0, stream>>>(Wq, Wt, 1024, 1024);
  k_transpose<<<dim3(16, 16), 256, 0, stream>>>(Wk, Wt + (1u << 20), 1024, 1024);
  k_transpose<<<dim3(16, 16), 256, 0, stream>>>(Wv, Wt + (2u << 20), 1024, 1024);
  k_transpose<<<dim3(16, 16), 256, 0, stream>>>(Wo, Wot, 1024, 1024);

  k_gemm_qkv<<<dim3(8, 64), 256, 0, stream>>>(abf, Wt, bq, bk, bv, QKVf);

  k_elu_norm<<<dim3(4096), 256, 0, stream>>>(Qf, qnb);
  k_elu_norm<<<dim3(2048), 256, 0, stream>>>(Kf, knb);
  k_transpose<<<dim3(16, 32), 256, 0, stream>>>(Vf, vTb, 2048, 1024);

  k_attn<<<dim3(32, 32), 256, 0, stream>>>(qnb, knb, vTb, ctxb);

  k_gemm_o<<<dim3(8, 32), 256, 0, stream>>>(ctxb, Wot, bo, Hf);

  k_out_ln<<<dim3(4096), 256, 0, stream>>>(Hf, target, lng, lnb, out);
}

// Round 4
// 128.641 us; speedup vs baseline: 2.2110x; 1.2335x over previous
//
#include <hip/hip_runtime.h>
#include <math.h>

typedef unsigned short u16t;
typedef __attribute__((ext_vector_type(8))) __bf16 bf16x8;
typedef __attribute__((ext_vector_type(4))) float f32x4;
typedef __attribute__((ext_vector_type(4))) unsigned short u16x4;

__device__ __forceinline__ u16t f2bf(float f) {
  union { float f; unsigned u; } v; v.f = f;
  return (u16t)((v.u + 0x7FFFu + ((v.u >> 16) & 1u)) >> 16);
}

// async global->LDS, 16B per lane; LDS dest linear (wave-uniform base + lane*16)
__device__ __forceinline__ void gload_lds16(const void* g, void* l) {
  __builtin_amdgcn_global_load_lds(
      (__attribute__((address_space(1))) void*)(uintptr_t)g,
      (__attribute__((address_space(3))) void*)(unsigned)(uintptr_t)l,
      16, 0, 0);
}

// ---------------- fused f32 -> bf16 convert of target|source|value ----------------
__global__ __launch_bounds__(256) void k_cvt3(const float* __restrict__ t0,
                                              const float* __restrict__ s0,
                                              const float* __restrict__ v0,
                                              u16t* __restrict__ out) {
  int row = blockIdx.x, t = threadIdx.x;
  const float* src = row < 4096 ? t0 + ((size_t)row << 10)
                   : row < 6144 ? s0 + ((size_t)(row - 4096) << 10)
                                : v0 + ((size_t)(row - 6144) << 10);
  f32x4 x = *reinterpret_cast<const f32x4*>(src + t * 4);
  u16x4 y;
#pragma unroll
  for (int j = 0; j < 4; j++) y[j] = f2bf(x[j]);
  *reinterpret_cast<u16x4*>(out + ((size_t)row << 10) + t * 4) = y;
}

// ---------------- fused 4x weight transpose f32[1024][1024] -> bf16 transposed ----
__global__ __launch_bounds__(256) void k_wtrans4(const float* __restrict__ Wq,
                                                 const float* __restrict__ Wk,
                                                 const float* __restrict__ Wv,
                                                 const float* __restrict__ Wo,
                                                 u16t* __restrict__ dstAll) {
  __shared__ u16t tile[64][68];
  int z = blockIdx.z;
  const float* in = z == 0 ? Wq : z == 1 ? Wk : z == 2 ? Wv : Wo;
  u16t* out = dstAll + ((size_t)z << 20);
  int r0 = blockIdx.y * 64, c0 = blockIdx.x * 64;
  int t = threadIdx.x;
  int rr = t >> 4, q4 = (t & 15) * 4;
#pragma unroll
  for (int i = 0; i < 4; i++) {
    int r = rr + i * 16;
    f32x4 x = *reinterpret_cast<const f32x4*>(&in[(size_t)(r0 + r) * 1024 + c0 + q4]);
#pragma unroll
    for (int j = 0; j < 4; j++) tile[r][q4 + j] = f2bf(x[j]);
  }
  __syncthreads();
#pragma unroll
  for (int i = 0; i < 4; i++) {
    int c = rr + i * 16;
    u16x4 y;
#pragma unroll
    for (int j = 0; j < 4; j++) y[j] = tile[q4 + j][c];
    *reinterpret_cast<u16x4*>(&out[(size_t)(c0 + c) * 1024 + r0 + q4]) = y;
  }
}

// ---------------- bf16 transpose [2048][1024] -> [1024][2048] (V) ----------------
__global__ __launch_bounds__(256) void k_vtrans(const u16t* __restrict__ in,
                                                u16t* __restrict__ out) {
  __shared__ u16t tile[64][68];
  int r0 = blockIdx.y * 64, c0 = blockIdx.x * 64;
  int t = threadIdx.x;
  int rr = t >> 4, q4 = (t & 15) * 4;
#pragma unroll
  for (int i = 0; i < 4; i++) {
    int r = rr + i * 16;
    u16x4 x = *reinterpret_cast<const u16x4*>(&in[(size_t)(r0 + r) * 1024 + c0 + q4]);
#pragma unroll
    for (int j = 0; j < 4; j++) tile[r][q4 + j] = x[j];
  }
  __syncthreads();
#pragma unroll
  for (int i = 0; i < 4; i++) {
    int c = rr + i * 16;
    u16x4 y;
#pragma unroll
    for (int j = 0; j < 4; j++) y[j] = tile[q4 + j][c];
    *reinterpret_cast<u16x4*>(&out[(size_t)(c0 + c) * 2048 + r0 + q4]) = y;
  }
}

// ---------------- 128x128x(K=1024) MFMA accumulate core ----------------
__device__ __forceinline__ void gemm128_acc(const u16t* __restrict__ A,
                                            const u16t* __restrict__ Bt,
                                            int m0, int n0, f32x4 acc[4][4]) {
  __shared__ __align__(16) u16t As[128 * 64];
  __shared__ __align__(16) u16t Bs[128 * 64];
  int t = threadIdx.x, lane = t & 63, w = t >> 6;
  int l15 = lane & 15, l16 = lane >> 4;
  int wr = w >> 1, wc = w & 1;
  int srow = t >> 3;
  int slc = ((t & 7) ^ (srow & 7)) << 3;

  for (int kt = 0; kt < 1024; kt += 64) {
#pragma unroll
    for (int i = 0; i < 4; i++) {
      int row = srow + i * 32;
      int c16 = (t + i * 256) * 16;
      gload_lds16(A + ((size_t)(m0 + row) << 10) + kt + slc, (char*)As + c16);
      gload_lds16(Bt + ((size_t)(n0 + row) << 10) + kt + slc, (char*)Bs + c16);
    }
    __syncthreads();
#pragma unroll
    for (int kk = 0; kk < 2; kk++) {
      bf16x8 af[4], bfr[4];
#pragma unroll
      for (int m = 0; m < 4; m++) {
        int ar = wr * 64 + m * 16 + l15;
        af[m] = *(const bf16x8*)((char*)As + ar * 128 + ((kk * 64 + l16 * 16) ^ ((ar & 7) << 4)));
      }
#pragma unroll
      for (int n = 0; n < 4; n++) {
        int br = wc * 64 + n * 16 + l15;
        bfr[n] = *(const bf16x8*)((char*)Bs + br * 128 + ((kk * 64 + l16 * 16) ^ ((br & 7) << 4)));
      }
#pragma unroll
      for (int m = 0; m < 4; m++)
#pragma unroll
        for (int n = 0; n < 4; n++)
          acc[m][n] = __builtin_amdgcn_mfma_f32_16x16x32_bf16(af[m], bfr[n], acc[m][n], 0, 0, 0);
    }
    __syncthreads();
  }
}

// QKV GEMM with fused bias + ELU + per-head L2-norm epilogue -> bf16
__global__ __launch_bounds__(256) void k_gemm_qkv(const u16t* __restrict__ A,
                                                  const u16t* __restrict__ Wt,
                                                  const float* __restrict__ b0,
                                                  const float* __restrict__ b1,
                                                  const float* __restrict__ b2,
                                                  u16t* __restrict__ out) {
  int m0 = blockIdx.y * 128, n0 = blockIdx.x * 128;
  int seg = (m0 >= 6144) ? 2 : (m0 >= 4096) ? 1 : 0;
  const float* bias = (seg == 0) ? b0 : (seg == 1) ? b1 : b2;
  f32x4 acc[4][4] = {};
  gemm128_acc(A, Wt + ((size_t)seg << 20), m0, n0, acc);

  int t = threadIdx.x, lane = t & 63, w = t >> 6;
  int l15 = lane & 15, l16 = lane >> 4;
  int wr = w >> 1, wc = w & 1;
  float bb[4];
#pragma unroll
  for (int n = 0; n < 4; n++) bb[n] = bias[n0 + wc * 64 + n * 16 + l15];
  if (seg < 2) {
    float scale0 = (seg == 0) ? 0.125f : 1.f;
#pragma unroll
    for (int m = 0; m < 4; m++) {
#pragma unroll
      for (int r = 0; r < 4; r++) {
        float e[4]; float ss = 0.f;
#pragma unroll
        for (int n = 0; n < 4; n++) {
          float x = acc[m][n][r] + bb[n];
          e[n] = x > 0.f ? x : (__expf(x) - 1.f);
          ss += e[n] * e[n];
        }
        ss += __shfl_xor(ss, 1); ss += __shfl_xor(ss, 2);
        ss += __shfl_xor(ss, 4); ss += __shfl_xor(ss, 8);
        float rinv = rsqrtf(ss) * scale0;
        int row = m0 + wr * 64 + m * 16 + l16 * 4 + r;
#pragma unroll
        for (int n = 0; n < 4; n++)
          out[((size_t)row << 10) + n0 + wc * 64 + n * 16 + l15] = f2bf(e[n] * rinv);
      }
    }
  } else {
#pragma unroll
    for (int m = 0; m < 4; m++) {
      int row = m0 + wr * 64 + m * 16 + l16 * 4;
#pragma unroll
      for (int n = 0; n < 4; n++) {
        int col = n0 + wc * 64 + n * 16 + l15;
#pragma unroll
        for (int r = 0; r < 4; r++)
          out[((size_t)(row + r) << 10) + col] = f2bf(acc[m][n][r] + bb[n]);
      }
    }
  }
}

// O-projection GEMM: ctx bf16 @ Wo^T + bo -> f32
__global__ __launch_bounds__(256) void k_gemm_o(const u16t* __restrict__ A,
                                                const u16t* __restrict__ Wt,
                                                const float* __restrict__ bias,
                                                float* __restrict__ C) {
  int m0 = blockIdx.y * 128, n0 = blockIdx.x * 128;
  f32x4 acc[4][4] = {};
  gemm128_acc(A, Wt, m0, n0, acc);
  int t = threadIdx.x, lane = t & 63, w = t >> 6;
  int l15 = lane & 15, l16 = lane >> 4;
  int wr = w >> 1, wc = w & 1;
#pragma unroll
  for (int n = 0; n < 4; n++) {
    int col = n0 + wc * 64 + n * 16 + l15;
    float bb = bias[col];
#pragma unroll
    for (int m = 0; m < 4; m++) {
      int row = m0 + wr * 64 + m * 16 + l16 * 4;
#pragma unroll
      for (int r = 0; r < 4; r++)
        C[((size_t)(row + r) << 10) + col] = acc[m][n][r] + bb;
    }
  }
}

// ---------------- fused attention ----------------
// 4 waves x 32 q-rows (2 Q-frags) = 128 q-rows/block; 64-key chunks, dbuf staging.
// Swapped QK^T; qn pre-scaled by 0.125; quadratic exp; rsum via ones-MFMA.
__global__ __launch_bounds__(256) void k_attn(const u16t* __restrict__ qn,
                                              const u16t* __restrict__ kn,
                                              const u16t* __restrict__ vT,
                                              u16t* __restrict__ ctx) {
  __shared__ __align__(16) u16t kls[2][64 * 64];
  __shared__ __align__(16) u16t vls[2][64 * 64];
  __shared__ __align__(16) u16t pls[4][2048];
  int bh = blockIdx.y, b = bh >> 4, h = bh & 15;
  int qt = blockIdx.x;
  int t = threadIdx.x, lane = t & 63, w = t >> 6;
  int l15 = lane & 15, l16 = lane >> 4;
  char* pbase = (char*)pls[w];

  bf16x8 qf[2][2];
#pragma unroll
  for (int f = 0; f < 2; f++) {
    const u16t* qp = qn + ((size_t)(b * 2048 + qt * 128 + w * 32 + f * 16 + l15) << 10) + (h << 6) + l16 * 8;
    qf[f][0] = *(const bf16x8*)qp;
    qf[f][1] = *(const bf16x8*)(qp + 32);
  }
  union { unsigned u[4]; bf16x8 v; } onesu;
  onesu.u[0] = onesu.u[1] = onesu.u[2] = onesu.u[3] = 0x3F803F80u;
  bf16x8 ones = onesu.v;

  f32x4 acc[2][4] = {};
  f32x4 rs[2] = {};
  int srow = t >> 3;
  int slc = ((t & 7) ^ (srow & 7)) << 3;
  int kswz = (l15 & 7) << 4;

#pragma unroll
  for (int i = 0; i < 2; i++) {
    int row = srow + i * 32;
    int c16 = (t + i * 256) * 16;
    gload_lds16(kn + ((size_t)row << 10) + (h << 6) + slc, (char*)kls[0] + c16);
    gload_lds16(vT + ((size_t)((h << 6) + row) << 11) + slc, (char*)vls[0] + c16);
  }
  __syncthreads();

  for (int tc = 0; tc < 32; tc++) {
    int cur = tc & 1;
    if (tc < 31) {
      int k0 = (tc + 1) * 64;
#pragma unroll
      for (int i = 0; i < 2; i++) {
        int row = srow + i * 32;
        int c16 = (t + i * 256) * 16;
        gload_lds16(kn + ((size_t)(k0 + row) << 10) + (h << 6) + slc, (char*)kls[cur ^ 1] + c16);
        gload_lds16(vT + ((size_t)((h << 6) + row) << 11) + k0 + slc, (char*)vls[cur ^ 1] + c16);
      }
    }
    char* kb = (char*)kls[cur];
    char* vb = (char*)vls[cur];

#pragma unroll
    for (int nf = 0; nf < 4; nf++) {
      int key = nf * 16 + l15;
      bf16x8 a0 = *(const bf16x8*)(kb + key * 128 + ((l16 * 16) ^ kswz));
      bf16x8 a1 = *(const bf16x8*)(kb + key * 128 + ((64 + l16 * 16) ^ kswz));
#pragma unroll
      for (int f = 0; f < 2; f++) {
        f32x4 s = {};
        s = __builtin_amdgcn_mfma_f32_16x16x32_bf16(a0, qf[f][0], s, 0, 0, 0);
        s = __builtin_amdgcn_mfma_f32_16x16x32_bf16(a1, qf[f][1], s, 0, 0, 0);
        float p[4];
#pragma unroll
        for (int r = 0; r < 4; r++)
          p[r] = fmaf(s[r], fmaf(s[r], 0.5f, 1.f), 1.f);
        unsigned w0, w1;
        asm("v_cvt_pk_bf16_f32 %0, %1, %2" : "=v"(w0) : "v"(p[0]), "v"(p[1]));
        asm("v_cvt_pk_bf16_f32 %0, %1, %2" : "=v"(w1) : "v"(p[2]), "v"(p[3]));
        union { unsigned u[2]; unsigned long long ull; } pw;
        pw.u[0] = w0; pw.u[1] = w1;
        *(unsigned long long*)(pbase + f * 2048 + l15 * 128 + ((nf * 32 + l16 * 8) ^ kswz)) = pw.ull;
      }
    }

#pragma unroll
    for (int kk = 0; kk < 2; kk++) {
      bf16x8 bvf[4];
#pragma unroll
      for (int nf = 0; nf < 4; nf++) {
        int e = nf * 16 + l15;
        bvf[nf] = *(const bf16x8*)(vb + e * 128 + ((kk * 64 + l16 * 16) ^ ((e & 7) << 4)));
      }
#pragma unroll
      for (int f = 0; f < 2; f++) {
        bf16x8 pa = *(const bf16x8*)(pbase + f * 2048 + l15 * 128 + ((kk * 64 + l16 * 16) ^ kswz));
#pragma unroll
        for (int nf = 0; nf < 4; nf++)
          acc[f][nf] = __builtin_amdgcn_mfma_f32_16x16x32_bf16(pa, bvf[nf], acc[f][nf], 0, 0, 0);
        rs[f] = __builtin_amdgcn_mfma_f32_16x16x32_bf16(pa, ones, rs[f], 0, 0, 0);
      }
    }
    __syncthreads();
  }

#pragma unroll
  for (int f = 0; f < 2; f++) {
    f32x4 ri;
#pragma unroll
    for (int r = 0; r < 4; r++) ri[r] = 1.f / rs[f][r];
    size_t orow = (size_t)b * 2048 + qt * 128 + w * 32 + f * 16 + l16 * 4;
#pragma unroll
    for (int nf = 0; nf < 4; nf++) {
      int col = (h << 6) + nf * 16 + l15;
#pragma unroll
      for (int r = 0; r < 4; r++)
        ctx[((orow + r) << 10) + col] = f2bf(acc[f][nf][r] * ri[r]);
    }
  }
}

// ---------------- residual + LayerNorm ----------------
__global__ __launch_bounds__(256) void k_out_ln(const float* __restrict__ Hh,
                                                const float* __restrict__ target,
                                                const float* __restrict__ g,
                                                const float* __restrict__ bb,
                                                float* __restrict__ out) {
  __shared__ float s_s[4], s_ss[4];
  int row = blockIdx.x, t = threadIdx.x, w = t >> 6;
  f32x4 hv = *reinterpret_cast<const f32x4*>(&Hh[(size_t)row * 1024 + t * 4]);
  f32x4 tv = *reinterpret_cast<const f32x4*>(&target[(size_t)row * 1024 + t * 4]);
  f32x4 x;
#pragma unroll
  for (int j = 0; j < 4; j++) x[j] = hv[j] + tv[j];
  float s = x[0] + x[1] + x[2] + x[3];
  float ss = x[0] * x[0] + x[1] * x[1] + x[2] * x[2] + x[3] * x[3];
#pragma unroll
  for (int m = 1; m < 64; m <<= 1) { s += __shfl_xor(s, m); ss += __shfl_xor(ss, m); }
  if ((t & 63) == 0) { s_s[w] = s; s_ss[w] = ss; }
  __syncthreads();
  s = s_s[0] + s_s[1] + s_s[2] + s_s[3];
  ss = s_ss[0] + s_ss[1] + s_ss[2] + s_ss[3];
  float mu = s * (1.f / 1024.f);
  float var = ss * (1.f / 1024.f) - mu * mu;
  float rsn = rsqrtf(var + 1e-12f);
  f32x4 gv = *reinterpret_cast<const f32x4*>(&g[t * 4]);
  f32x4 bv = *reinterpret_cast<const f32x4*>(&bb[t * 4]);
  f32x4 o;
#pragma unroll
  for (int j = 0; j < 4; j++) o[j] = (x[j] - mu) * rsn * gv[j] + bv[j];
  *reinterpret_cast<f32x4*>(&out[(size_t)row * 1024 + t * 4]) = o;
}

extern "C" void kernel_launch(void* const* d_in, const int* in_sizes, int n_in,
                              void* d_out, int out_size, void* d_ws, size_t ws_size,
                              hipStream_t stream) {
  const float* target = (const float*)d_in[0];
  const float* source = (const float*)d_in[1];
  const float* value  = (const float*)d_in[2];
  const float* Wq = (const float*)d_in[3];
  const float* bq = (const float*)d_in[4];
  const float* Wk = (const float*)d_in[5];
  const float* bk = (const float*)d_in[6];
  const float* Wv = (const float*)d_in[7];
  const float* bvp = (const float*)d_in[8];
  const float* Wo = (const float*)d_in[9];
  const float* bo = (const float*)d_in[10];
  const float* lng = (const float*)d_in[11];
  const float* lnb = (const float*)d_in[12];
  float* out = (float*)d_out;
  char* ws = (char*)d_ws;
  const size_t MB = 1u << 20;

  // ws layout (68 MB):
  //  [0,16)   abf   bf16 [8192][1024]  target|source|value
  //  [16,24)  Wt    bf16 4x[1024][1024] transposed (Wq,Wk,Wv,Wo)
  //  [24,40)  qkvnb bf16 [8192][1024]: qn 0-4095, kn 4096-6143, vbf 6144-8191
  //  [40,44)  vTb   bf16 [1024][2048]
  //  [44,52)  ctxb  bf16 [4096][1024]
  //  [52,68)  Hf    f32  [4096][1024]
  u16t* abf   = (u16t*)ws;
  u16t* Wt    = (u16t*)(ws + 16 * MB);
  u16t* Wot   = Wt + ((size_t)3 << 20);
  u16t* qkvnb = (u16t*)(ws + 24 * MB);
  u16t* qnb   = qkvnb;
  u16t* knb   = qkvnb + ((size_t)4096 << 10);
  u16t* vbf   = qkvnb + ((size_t)6144 << 10);
  u16t* vTb   = (u16t*)(ws + 40 * MB);
  u16t* ctxb  = (u16t*)(ws + 44 * MB);
  float* Hf   = (float*)(ws + 52 * MB);

  k_cvt3<<<dim3(8192), 256, 0, stream>>>(target, source, value, abf);
  k_wtrans4<<<dim3(16, 16, 4), 256, 0, stream>>>(Wq, Wk, Wv, Wo, Wt);
  k_gemm_qkv<<<dim3(8, 64), 256, 0, stream>>>(abf, Wt, bq, bk, bvp, qkvnb);
  k_vtrans<<<dim3(16, 32), 256, 0, stream>>>(vbf, vTb);
  k_attn<<<dim3(16, 32), 256, 0, stream>>>(qnb, knb, vTb, ctxb);
  k_gemm_o<<<dim3(8, 32), 256, 0, stream>>>(ctxb, Wot, bo, Hf);
  k_out_ln<<<dim3(4096), 256, 0, stream>>>(Hf, target, lng, lnb, out);
}

// Round 5
// 119.961 us; speedup vs baseline: 2.3710x; 1.0724x over previous
//
#include <hip/hip_runtime.h>
#include <math.h>

typedef unsigned short u16t;
typedef __attribute__((ext_vector_type(8))) __bf16 bf16x8;
typedef __attribute__((ext_vector_type(4))) float f32x4;
typedef __attribute__((ext_vector_type(16))) float f32x16;
typedef __attribute__((ext_vector_type(4))) unsigned short u16x4;

__device__ __forceinline__ u16t f2bf(float f) {
  union { float f; unsigned u; } v; v.f = f;
  return (u16t)((v.u + 0x7FFFu + ((v.u >> 16) & 1u)) >> 16);
}

// async global->LDS, 16B per lane; LDS dest linear (wave-uniform base + lane*16)
__device__ __forceinline__ void gload_lds16(const void* g, void* l) {
  __builtin_amdgcn_global_load_lds(
      (__attribute__((address_space(1))) void*)(uintptr_t)g,
      (__attribute__((address_space(3))) void*)(unsigned)(uintptr_t)l,
      16, 0, 0);
}

// v_permlane32_swap_b32: a<-[a.lo | b.lo(from lanes 0-31)], b<-[a.hi | b.hi]
__device__ __forceinline__ void plswap(unsigned &a, unsigned &b) {
  asm("v_permlane32_swap_b32 %0, %1" : "+v"(a), "+v"(b));
}

// ---------------- fused f32 -> bf16 convert of target|source|value ----------------
__global__ __launch_bounds__(256) void k_cvt3(const float* __restrict__ t0,
                                              const float* __restrict__ s0,
                                              const float* __restrict__ v0,
                                              u16t* __restrict__ out) {
  int row = blockIdx.x, t = threadIdx.x;
  const float* src = row < 4096 ? t0 + ((size_t)row << 10)
                   : row < 6144 ? s0 + ((size_t)(row - 4096) << 10)
                                : v0 + ((size_t)(row - 6144) << 10);
  f32x4 x = *reinterpret_cast<const f32x4*>(src + t * 4);
  u16x4 y;
#pragma unroll
  for (int j = 0; j < 4; j++) y[j] = f2bf(x[j]);
  *reinterpret_cast<u16x4*>(out + ((size_t)row << 10) + t * 4) = y;
}

// ---------------- fused 4x weight transpose f32[1024][1024] -> bf16 transposed ----
__global__ __launch_bounds__(256) void k_wtrans4(const float* __restrict__ Wq,
                                                 const float* __restrict__ Wk,
                                                 const float* __restrict__ Wv,
                                                 const float* __restrict__ Wo,
                                                 u16t* __restrict__ dstAll) {
  __shared__ u16t tile[64][68];
  int z = blockIdx.z;
  const float* in = z == 0 ? Wq : z == 1 ? Wk : z == 2 ? Wv : Wo;
  u16t* out = dstAll + ((size_t)z << 20);
  int r0 = blockIdx.y * 64, c0 = blockIdx.x * 64;
  int t = threadIdx.x;
  int rr = t >> 4, q4 = (t & 15) * 4;
#pragma unroll
  for (int i = 0; i < 4; i++) {
    int r = rr + i * 16;
    f32x4 x = *reinterpret_cast<const f32x4*>(&in[(size_t)(r0 + r) * 1024 + c0 + q4]);
#pragma unroll
    for (int j = 0; j < 4; j++) tile[r][q4 + j] = f2bf(x[j]);
  }
  __syncthreads();
#pragma unroll
  for (int i = 0; i < 4; i++) {
    int c = rr + i * 16;
    u16x4 y;
#pragma unroll
    for (int j = 0; j < 4; j++) y[j] = tile[q4 + j][c];
    *reinterpret_cast<u16x4*>(&out[(size_t)(c0 + c) * 1024 + r0 + q4]) = y;
  }
}

// ---------------- bf16 transpose [2048][1024] -> [1024][2048] (V) ----------------
__global__ __launch_bounds__(256) void k_vtrans(const u16t* __restrict__ in,
                                                u16t* __restrict__ out) {
  __shared__ u16t tile[64][68];
  int r0 = blockIdx.y * 64, c0 = blockIdx.x * 64;
  int t = threadIdx.x;
  int rr = t >> 4, q4 = (t & 15) * 4;
#pragma unroll
  for (int i = 0; i < 4; i++) {
    int r = rr + i * 16;
    u16x4 x = *reinterpret_cast<const u16x4*>(&in[(size_t)(r0 + r) * 1024 + c0 + q4]);
#pragma unroll
    for (int j = 0; j < 4; j++) tile[r][q4 + j] = x[j];
  }
  __syncthreads();
#pragma unroll
  for (int i = 0; i < 4; i++) {
    int c = rr + i * 16;
    u16x4 y;
#pragma unroll
    for (int j = 0; j < 4; j++) y[j] = tile[q4 + j][c];
    *reinterpret_cast<u16x4*>(&out[(size_t)(c0 + c) * 2048 + r0 + q4]) = y;
  }
}

// ---------------- 128x128x(K=1024) MFMA core, 2-phase pipelined ----------------
__device__ __forceinline__ void gemm128_acc(const u16t* __restrict__ A,
                                            const u16t* __restrict__ Bt,
                                            int m0, int n0, f32x4 acc[4][4]) {
  __shared__ __align__(16) u16t As[2][128 * 64];
  __shared__ __align__(16) u16t Bs[2][128 * 64];
  int t = threadIdx.x, lane = t & 63, w = t >> 6;
  int l15 = lane & 15, l16 = lane >> 4;
  int wr = w >> 1, wc = w & 1;
  int srow = t >> 3;
  int slc = ((t & 7) ^ (srow & 7)) << 3;

  // prologue: stage K-tile 0 into buf 0
#pragma unroll
  for (int i = 0; i < 4; i++) {
    int row = srow + i * 32;
    int c16 = (t + i * 256) * 16;
    gload_lds16(A + ((size_t)(m0 + row) << 10) + slc, (char*)As[0] + c16);
    gload_lds16(Bt + ((size_t)(n0 + row) << 10) + slc, (char*)Bs[0] + c16);
  }
  __syncthreads();

  for (int ki = 0; ki < 16; ki++) {
    int cur = ki & 1;
    if (ki < 15) {
      int kt = (ki + 1) << 6;
#pragma unroll
      for (int i = 0; i < 4; i++) {
        int row = srow + i * 32;
        int c16 = (t + i * 256) * 16;
        gload_lds16(A + ((size_t)(m0 + row) << 10) + kt + slc, (char*)As[cur ^ 1] + c16);
        gload_lds16(Bt + ((size_t)(n0 + row) << 10) + kt + slc, (char*)Bs[cur ^ 1] + c16);
      }
    }
#pragma unroll
    for (int kk = 0; kk < 2; kk++) {
      bf16x8 af[4], bfr[4];
#pragma unroll
      for (int m = 0; m < 4; m++) {
        int ar = wr * 64 + m * 16 + l15;
        af[m] = *(const bf16x8*)((char*)As[cur] + ar * 128 + ((kk * 64 + l16 * 16) ^ ((ar & 7) << 4)));
      }
#pragma unroll
      for (int n = 0; n < 4; n++) {
        int br = wc * 64 + n * 16 + l15;
        bfr[n] = *(const bf16x8*)((char*)Bs[cur] + br * 128 + ((kk * 64 + l16 * 16) ^ ((br & 7) << 4)));
      }
#pragma unroll
      for (int m = 0; m < 4; m++)
#pragma unroll
        for (int n = 0; n < 4; n++)
          acc[m][n] = __builtin_amdgcn_mfma_f32_16x16x32_bf16(af[m], bfr[n], acc[m][n], 0, 0, 0);
    }
    __syncthreads();
  }
}

// QKV GEMM with fused bias + ELU + per-head L2-norm epilogue -> bf16
__global__ __launch_bounds__(256) void k_gemm_qkv(const u16t* __restrict__ A,
                                                  const u16t* __restrict__ Wt,
                                                  const float* __restrict__ b0,
                                                  const float* __restrict__ b1,
                                                  const float* __restrict__ b2,
                                                  u16t* __restrict__ out) {
  int m0 = blockIdx.y * 128, n0 = blockIdx.x * 128;
  int seg = (m0 >= 6144) ? 2 : (m0 >= 4096) ? 1 : 0;
  const float* bias = (seg == 0) ? b0 : (seg == 1) ? b1 : b2;
  f32x4 acc[4][4] = {};
  gemm128_acc(A, Wt + ((size_t)seg << 20), m0, n0, acc);

  int t = threadIdx.x, lane = t & 63, w = t >> 6;
  int l15 = lane & 15, l16 = lane >> 4;
  int wr = w >> 1, wc = w & 1;
  float bb[4];
#pragma unroll
  for (int n = 0; n < 4; n++) bb[n] = bias[n0 + wc * 64 + n * 16 + l15];
  if (seg < 2) {
    float scale0 = (seg == 0) ? 0.125f : 1.f;
#pragma unroll
    for (int m = 0; m < 4; m++) {
#pragma unroll
      for (int r = 0; r < 4; r++) {
        float e[4]; float ss = 0.f;
#pragma unroll
        for (int n = 0; n < 4; n++) {
          float x = acc[m][n][r] + bb[n];
          e[n] = x > 0.f ? x : (__expf(x) - 1.f);
          ss += e[n] * e[n];
        }
        ss += __shfl_xor(ss, 1); ss += __shfl_xor(ss, 2);
        ss += __shfl_xor(ss, 4); ss += __shfl_xor(ss, 8);
        float rinv = rsqrtf(ss) * scale0;
        int row = m0 + wr * 64 + m * 16 + l16 * 4 + r;
#pragma unroll
        for (int n = 0; n < 4; n++)
          out[((size_t)row << 10) + n0 + wc * 64 + n * 16 + l15] = f2bf(e[n] * rinv);
      }
    }
  } else {
#pragma unroll
    for (int m = 0; m < 4; m++) {
      int row = m0 + wr * 64 + m * 16 + l16 * 4;
#pragma unroll
      for (int n = 0; n < 4; n++) {
        int col = n0 + wc * 64 + n * 16 + l15;
#pragma unroll
        for (int r = 0; r < 4; r++)
          out[((size_t)(row + r) << 10) + col] = f2bf(acc[m][n][r] + bb[n]);
      }
    }
  }
}

// O-projection GEMM: ctx bf16 @ Wo^T + bo -> f32
__global__ __launch_bounds__(256) void k_gemm_o(const u16t* __restrict__ A,
                                                const u16t* __restrict__ Wt,
                                                const float* __restrict__ bias,
                                                float* __restrict__ C) {
  int m0 = blockIdx.y * 128, n0 = blockIdx.x * 128;
  f32x4 acc[4][4] = {};
  gemm128_acc(A, Wt, m0, n0, acc);
  int t = threadIdx.x, lane = t & 63, w = t >> 6;
  int l15 = lane & 15, l16 = lane >> 4;
  int wr = w >> 1, wc = w & 1;
#pragma unroll
  for (int n = 0; n < 4; n++) {
    int col = n0 + wc * 64 + n * 16 + l15;
    float bb = bias[col];
#pragma unroll
    for (int m = 0; m < 4; m++) {
      int row = m0 + wr * 64 + m * 16 + l16 * 4;
#pragma unroll
      for (int r = 0; r < 4; r++)
        C[((size_t)(row + r) << 10) + col] = acc[m][n][r] + bb;
    }
  }
}

// ---------------- fused attention, 32x32x16 MFMA, P in registers ----------------
// 2 waves x 32 q-rows; 64-key chunks; swapped QK^T (S^T = K.Q^T);
// P via cvt_pk + permlane32_swap (no LDS); rsum via ones-MFMA (same C-layout as O).
__global__ __launch_bounds__(128) void k_attn(const u16t* __restrict__ qn,
                                              const u16t* __restrict__ kn,
                                              const u16t* __restrict__ vT,
                                              u16t* __restrict__ ctx) {
  __shared__ __align__(16) u16t kls[2][64 * 64];
  __shared__ __align__(16) u16t vls[2][64 * 64];
  int bh = blockIdx.y, b = bh >> 4, h = bh & 15;
  int qt = blockIdx.x;
  int t = threadIdx.x, lane = t & 63, w = t >> 6;
  int l31 = lane & 31, hi = lane >> 5;
  int kxor = (l31 & 7) << 4;

  // Q B-frags: lane holds col=q=l31, k=e=ks*16+hi*8+j
  int qrow = b * 2048 + qt * 64 + w * 32 + l31;
  const u16t* qp = qn + ((size_t)qrow << 10) + (h << 6) + hi * 8;
  bf16x8 qf[4];
#pragma unroll
  for (int ks = 0; ks < 4; ks++) qf[ks] = *(const bf16x8*)(qp + ks * 16);

  union { unsigned u[4]; bf16x8 v; } onesu;
  onesu.u[0] = onesu.u[1] = onesu.u[2] = onesu.u[3] = 0x3F803F80u;
  bf16x8 ones = onesu.v;

  f32x16 o0 = {}, o1 = {}, rs = {};

  // prologue: stage chunk 0
#pragma unroll
  for (int j = 0; j < 4; j++) {
    int idx = t + j * 128;
    int row = idx >> 3;
    int sc = ((idx & 7) ^ (row & 7)) << 3;
    gload_lds16(kn + ((size_t)row << 10) + (h << 6) + sc, (char*)kls[0] + idx * 16);
    gload_lds16(vT + ((size_t)((h << 6) + row) << 11) + sc, (char*)vls[0] + idx * 16);
  }
  __syncthreads();

  for (int tc = 0; tc < 32; tc++) {
    int cur = tc & 1;
    if (tc < 31) {
      int k0 = (tc + 1) << 6;
#pragma unroll
      for (int j = 0; j < 4; j++) {
        int idx = t + j * 128;
        int row = idx >> 3;
        int sc = ((idx & 7) ^ (row & 7)) << 3;
        gload_lds16(kn + ((size_t)(k0 + row) << 10) + (h << 6) + sc, (char*)kls[cur ^ 1] + idx * 16);
        gload_lds16(vT + ((size_t)((h << 6) + row) << 11) + k0 + sc, (char*)vls[cur ^ 1] + idx * 16);
      }
    }
    const char* kb = (const char*)kls[cur];
    const char* vb = (const char*)vls[cur];

    // S^T = K . Q^T : 2 key-tiles x 4 k-steps
    f32x16 s0 = {}, s1 = {};
#pragma unroll
    for (int ks = 0; ks < 4; ks++) {
      int coff = ks * 32 + hi * 16;
      bf16x8 a0 = *(const bf16x8*)(kb + l31 * 128 + (coff ^ kxor));
      bf16x8 a1 = *(const bf16x8*)(kb + (32 + l31) * 128 + (coff ^ kxor));
      s0 = __builtin_amdgcn_mfma_f32_32x32x16_bf16(a0, qf[ks], s0, 0, 0, 0);
      s1 = __builtin_amdgcn_mfma_f32_32x32x16_bf16(a1, qf[ks], s1, 0, 0, 0);
    }

    // quadratic exp (|s|<=0.13) -> bf16 pack -> permlane32_swap => PV A-frags
    bf16x8 pf[4];
#pragma unroll
    for (int tile = 0; tile < 2; tile++) {
      const f32x16& s = tile ? s1 : s0;
      float p[16];
#pragma unroll
      for (int i = 0; i < 16; i++) p[i] = fmaf(s[i], fmaf(s[i], 0.5f, 1.f), 1.f);
      unsigned m[8];
#pragma unroll
      for (int i = 0; i < 8; i++)
        asm("v_cvt_pk_bf16_f32 %0, %1, %2" : "=v"(m[i]) : "v"(p[2 * i]), "v"(p[2 * i + 1]));
      plswap(m[0], m[2]); plswap(m[1], m[3]);
      plswap(m[4], m[6]); plswap(m[5], m[7]);
      union { unsigned u[4]; bf16x8 v; } fa, fb;
      fa.u[0] = m[0]; fa.u[1] = m[1]; fa.u[2] = m[2]; fa.u[3] = m[3];
      fb.u[0] = m[4]; fb.u[1] = m[5]; fb.u[2] = m[6]; fb.u[3] = m[7];
      pf[tile * 2] = fa.v; pf[tile * 2 + 1] = fb.v;
    }

    // PV + rsum: 4 k-steps of 16 keys
#pragma unroll
    for (int ks = 0; ks < 4; ks++) {
      int coff = ks * 32 + hi * 16;
      bf16x8 v0 = *(const bf16x8*)(vb + l31 * 128 + (coff ^ kxor));
      bf16x8 v1 = *(const bf16x8*)(vb + (32 + l31) * 128 + (coff ^ kxor));
      o0 = __builtin_amdgcn_mfma_f32_32x32x16_bf16(pf[ks], v0, o0, 0, 0, 0);
      o1 = __builtin_amdgcn_mfma_f32_32x32x16_bf16(pf[ks], v1, o1, 0, 0, 0);
      rs = __builtin_amdgcn_mfma_f32_32x32x16_bf16(pf[ks], ones, rs, 0, 0, 0);
    }
    __syncthreads();
  }

  // epilogue: divide by rsum (same C-layout) and store bf16
#pragma unroll
  for (int r = 0; r < 16; r++) {
    float ri = 1.f / rs[r];
    int q = (r & 3) + 8 * (r >> 2) + 4 * hi;
    size_t row = (size_t)(b * 2048 + qt * 64 + w * 32 + q);
    u16t* cp = ctx + (row << 10) + (h << 6) + l31;
    cp[0] = f2bf(o0[r] * ri);
    cp[32] = f2bf(o1[r] * ri);
  }
}

// ---------------- residual + LayerNorm ----------------
__global__ __launch_bounds__(256) void k_out_ln(const float* __restrict__ Hh,
                                                const float* __restrict__ target,
                                                const float* __restrict__ g,
                                                const float* __restrict__ bb,
                                                float* __restrict__ out) {
  __shared__ float s_s[4], s_ss[4];
  int row = blockIdx.x, t = threadIdx.x, w = t >> 6;
  f32x4 hv = *reinterpret_cast<const f32x4*>(&Hh[(size_t)row * 1024 + t * 4]);
  f32x4 tv = *reinterpret_cast<const f32x4*>(&target[(size_t)row * 1024 + t * 4]);
  f32x4 x;
#pragma unroll
  for (int j = 0; j < 4; j++) x[j] = hv[j] + tv[j];
  float s = x[0] + x[1] + x[2] + x[3];
  float ss = x[0] * x[0] + x[1] * x[1] + x[2] * x[2] + x[3] * x[3];
#pragma unroll
  for (int m = 1; m < 64; m <<= 1) { s += __shfl_xor(s, m); ss += __shfl_xor(ss, m); }
  if ((t & 63) == 0) { s_s[w] = s; s_ss[w] = ss; }
  __syncthreads();
  s = s_s[0] + s_s[1] + s_s[2] + s_s[3];
  ss = s_ss[0] + s_ss[1] + s_ss[2] + s_ss[3];
  float mu = s * (1.f / 1024.f);
  float var = ss * (1.f / 1024.f) - mu * mu;
  float rsn = rsqrtf(var + 1e-12f);
  f32x4 gv = *reinterpret_cast<const f32x4*>(&g[t * 4]);
  f32x4 bv = *reinterpret_cast<const f32x4*>(&bb[t * 4]);
  f32x4 o;
#pragma unroll
  for (int j = 0; j < 4; j++) o[j] = (x[j] - mu) * rsn * gv[j] + bv[j];
  *reinterpret_cast<f32x4*>(&out[(size_t)row * 1024 + t * 4]) = o;
}

extern "C" void kernel_launch(void* const* d_in, const int* in_sizes, int n_in,
                              void* d_out, int out_size, void* d_ws, size_t ws_size,
                              hipStream_t stream) {
  const float* target = (const float*)d_in[0];
  const float* source = (const float*)d_in[1];
  const float* value  = (const float*)d_in[2];
  const float* Wq = (const float*)d_in[3];
  const float* bq = (const float*)d_in[4];
  const float* Wk = (const float*)d_in[5];
  const float* bk = (const float*)d_in[6];
  const float* Wv = (const float*)d_in[7];
  const float* bvp = (const float*)d_in[8];
  const float* Wo = (const float*)d_in[9];
  const float* bo = (const float*)d_in[10];
  const float* lng = (const float*)d_in[11];
  const float* lnb = (const float*)d_in[12];
  float* out = (float*)d_out;
  char* ws = (char*)d_ws;
  const size_t MB = 1u << 20;

  u16t* abf   = (u16t*)ws;                       // [0,16) bf16 target|source|value
  u16t* Wt    = (u16t*)(ws + 16 * MB);           // [16,24) 4x transposed weights
  u16t* Wot   = Wt + ((size_t)3 << 20);
  u16t* qkvnb = (u16t*)(ws + 24 * MB);           // [24,40) qn|kn|vbf
  u16t* qnb   = qkvnb;
  u16t* knb   = qkvnb + ((size_t)4096 << 10);
  u16t* vbf   = qkvnb + ((size_t)6144 << 10);
  u16t* vTb   = (u16t*)(ws + 40 * MB);           // [40,44) vT [1024][2048]
  u16t* ctxb  = (u16t*)(ws + 44 * MB);           // [44,52)
  float* Hf   = (float*)(ws + 52 * MB);          // [52,68)

  k_cvt3<<<dim3(8192), 256, 0, stream>>>(target, source, value, abf);
  k_wtrans4<<<dim3(16, 16, 4), 256, 0, stream>>>(Wq, Wk, Wv, Wo, Wt);
  k_gemm_qkv<<<dim3(8, 64), 256, 0, stream>>>(abf, Wt, bq, bk, bvp, qkvnb);
  k_vtrans<<<dim3(16, 32), 256, 0, stream>>>(vbf, vTb);
  k_attn<<<dim3(32, 32), 128, 0, stream>>>(qnb, knb, vTb, ctxb);
  k_gemm_o<<<dim3(8, 32), 256, 0, stream>>>(ctxb, Wot, bo, Hf);
  k_out_ln<<<dim3(4096), 256, 0, stream>>>(Hf, target, lng, lnb, out);
}